// Round 1
// baseline (136.721 us; speedup 1.0000x reference)
//
#include <hip/hip_runtime.h>

// Triplet margin loss: mean(relu(|a-p|^2 - |a-n|^2 + MARGIN)) over T triplets.
// batch: (N=4096, D=1024) fp32; triplets: (T, 3) int32 indices.
// Strategy: one wave (64 lanes) per triplet; each lane reads 4 float4 chunks
// per row (64 lanes * 4 * 4 floats = 1024). Rows are 4KB contiguous -> fully
// coalesced; batch (16MB) lives in L2/L3 so gathers hit cache.

constexpr float MARGIN = 0.2f;
constexpr int D = 1024;
constexpr int WAVES_PER_BLOCK = 4;   // 256 threads

__global__ __launch_bounds__(256)
void triplet_partial_kernel(const float* __restrict__ batch,
                            const int*   __restrict__ trip,
                            float*       __restrict__ partials,
                            int T)
{
    const int lane = threadIdx.x & 63;
    const int wib  = threadIdx.x >> 6;                       // wave in block
    const int wave_id = blockIdx.x * WAVES_PER_BLOCK + wib;  // global wave
    const int n_waves = gridDim.x * WAVES_PER_BLOCK;

    float acc = 0.0f;

    for (int t = wave_id; t < T; t += n_waves) {
        const int ia = trip[3 * t + 0];
        const int ip = trip[3 * t + 1];
        const int in_ = trip[3 * t + 2];

        const float4* __restrict__ A = (const float4*)(batch + (size_t)ia * D);
        const float4* __restrict__ P = (const float4*)(batch + (size_t)ip * D);
        const float4* __restrict__ Nv = (const float4*)(batch + (size_t)in_ * D);

        float dap = 0.0f, dan = 0.0f;
        #pragma unroll
        for (int c = 0; c < 4; ++c) {
            const int idx = lane + c * 64;   // float4 index within the row
            float4 av = A[idx];
            float4 pv = P[idx];
            float4 nv = Nv[idx];
            float d;
            d = av.x - pv.x; dap += d * d;
            d = av.y - pv.y; dap += d * d;
            d = av.z - pv.z; dap += d * d;
            d = av.w - pv.w; dap += d * d;
            d = av.x - nv.x; dan += d * d;
            d = av.y - nv.y; dan += d * d;
            d = av.z - nv.z; dan += d * d;
            d = av.w - nv.w; dan += d * d;
        }

        // Reduce (dap - dan) across the 64-lane wave (butterfly: all lanes
        // end with the total, deterministic order).
        float diff = dap - dan;
        #pragma unroll
        for (int off = 32; off > 0; off >>= 1)
            diff += __shfl_xor(diff, off, 64);

        const float loss = diff + MARGIN;
        acc += loss > 0.0f ? loss : 0.0f;
    }

    // acc is wave-uniform after the butterfly; reduce the 4 waves via LDS.
    __shared__ float s[WAVES_PER_BLOCK];
    if (lane == 0) s[wib] = acc;
    __syncthreads();
    if (threadIdx.x == 0)
        partials[blockIdx.x] = (s[0] + s[1]) + (s[2] + s[3]);
}

__global__ __launch_bounds__(256)
void reduce_final_kernel(const float* __restrict__ partials, int n,
                         float* __restrict__ out, float invT)
{
    __shared__ float s[256];
    float acc = 0.0f;
    for (int i = threadIdx.x; i < n; i += 256)
        acc += partials[i];
    s[threadIdx.x] = acc;
    __syncthreads();
    #pragma unroll
    for (int stride = 128; stride > 0; stride >>= 1) {
        if (threadIdx.x < stride) s[threadIdx.x] += s[threadIdx.x + stride];
        __syncthreads();
    }
    if (threadIdx.x == 0) out[0] = s[0] * invT;
}

extern "C" void kernel_launch(void* const* d_in, const int* in_sizes, int n_in,
                              void* d_out, int out_size, void* d_ws, size_t ws_size,
                              hipStream_t stream)
{
    const float* batch = (const float*)d_in[0];
    const int*   trip  = (const int*)d_in[1];
    float* out = (float*)d_out;
    float* partials = (float*)d_ws;

    const int T = in_sizes[1] / 3;

    const int blocks = 2048;  // 8192 waves, ~12 triplets each; fills 256 CUs
    triplet_partial_kernel<<<blocks, 256, 0, stream>>>(batch, trip, partials, T);
    reduce_final_kernel<<<1, 256, 0, stream>>>(partials, blocks, out, 1.0f / (float)T);
}

// Round 2
// 55.179 us; speedup vs baseline: 2.4778x; 2.4778x over previous
//
#include <hip/hip_runtime.h>

// Triplet margin loss: mean(relu(|a-p|^2 - |a-n|^2 + MARGIN)).
// batch: (N=4096, D=1024) fp32 (16 MB); triplets: (T=100000, 3) int32.
//
// R1 finding: single-pass gather refetches ~455 MB from L3 per dispatch
// (16 MB batch > 4 MB per-XCD L2; random gathers thrash). Fix: partition D
// into 8 chunks of 128 floats; chunk c is processed only by blocks with
// blockIdx.x % 8 == c, which land on XCD c (round-robin dispatch). Each XCD's
// working slice is 2 MB -> fits its private L2. Phase 2 sums the 8 chunk
// partials per triplet, applies margin+relu, and reduces to the mean.

constexpr float MARGIN = 0.2f;
constexpr int D = 1024;
constexpr int NCHUNK = 8;            // = number of XCDs
constexpr int CHUNK = D / NCHUNK;    // 128 floats = 512 B slice per row

// ---------------- Phase 1: per-(triplet, chunk) partial diffs ----------------
// 16 lanes per triplet-chunk: 128 floats = 16 lanes x 2 float4.
__global__ __launch_bounds__(256)
void triplet_chunk_kernel(const float* __restrict__ batch,
                          const int*   __restrict__ trip,
                          float*       __restrict__ chunk_part, // [NCHUNK][T]
                          int T)
{
    const int c     = blockIdx.x & (NCHUNK - 1);  // chunk == XCD (round-robin)
    const int bslot = blockIdx.x >> 3;            // block index within chunk
    const int nslot = gridDim.x >> 3;
    const int lane  = threadIdx.x & 63;
    const int wib   = threadIdx.x >> 6;           // wave in block (0..3)
    const int g     = lane >> 4;                  // triplet subgroup (0..3)
    const int s     = lane & 15;                  // sublane within group

    const float* base = batch + c * CHUNK;
    const int stride = nslot * 16;                // triplets per grid sweep

    for (int t = bslot * 16 + wib * 4 + g; t < T; t += stride) {
        const int ia  = trip[3 * t + 0];
        const int ip  = trip[3 * t + 1];
        const int in_ = trip[3 * t + 2];

        const float4* A  = (const float4*)(base + (size_t)ia * D);
        const float4* P  = (const float4*)(base + (size_t)ip * D);
        const float4* Nv = (const float4*)(base + (size_t)in_ * D);

        float dap = 0.0f, dan = 0.0f;
        #pragma unroll
        for (int k = 0; k < 2; ++k) {
            const int idx = s + k * 16;           // float4 index in the chunk
            float4 av = A[idx];
            float4 pv = P[idx];
            float4 nv = Nv[idx];
            float d;
            d = av.x - pv.x; dap += d * d;
            d = av.y - pv.y; dap += d * d;
            d = av.z - pv.z; dap += d * d;
            d = av.w - pv.w; dap += d * d;
            d = av.x - nv.x; dan += d * d;
            d = av.y - nv.y; dan += d * d;
            d = av.z - nv.z; dan += d * d;
            d = av.w - nv.w; dan += d * d;
        }

        // Reduce within the 16-lane group (xor offsets < 16 stay in-group).
        float diff = dap - dan;
        diff += __shfl_xor(diff, 1, 64);
        diff += __shfl_xor(diff, 2, 64);
        diff += __shfl_xor(diff, 4, 64);
        diff += __shfl_xor(diff, 8, 64);

        if (s == 0) chunk_part[(size_t)c * T + t] = diff;
    }
}

// ------------- Phase 2: sum chunks, margin+relu, per-block partial -----------
__global__ __launch_bounds__(256)
void chunk_reduce_kernel(const float* __restrict__ chunk_part,
                         float*       __restrict__ part2, int T)
{
    float acc = 0.0f;
    for (int t = blockIdx.x * 256 + threadIdx.x; t < T; t += gridDim.x * 256) {
        float sum = MARGIN;
        #pragma unroll
        for (int c = 0; c < NCHUNK; ++c) sum += chunk_part[(size_t)c * T + t];
        acc += sum > 0.0f ? sum : 0.0f;
    }
    __shared__ float s[256];
    s[threadIdx.x] = acc;
    __syncthreads();
    #pragma unroll
    for (int st = 128; st > 0; st >>= 1) {
        if (threadIdx.x < st) s[threadIdx.x] += s[threadIdx.x + st];
        __syncthreads();
    }
    if (threadIdx.x == 0) part2[blockIdx.x] = s[0];
}

// ---------------- Phase 3: final scalar ----------------
__global__ __launch_bounds__(256)
void final_mean_kernel(const float* __restrict__ part2, int n,
                       float* __restrict__ out, float invT)
{
    __shared__ float s[256];
    float acc = 0.0f;
    for (int i = threadIdx.x; i < n; i += 256) acc += part2[i];
    s[threadIdx.x] = acc;
    __syncthreads();
    #pragma unroll
    for (int st = 128; st > 0; st >>= 1) {
        if (threadIdx.x < st) s[threadIdx.x] += s[threadIdx.x + st];
        __syncthreads();
    }
    if (threadIdx.x == 0) out[0] = s[0] * invT;
}

// ---------------- Fallback (R1 kernel): one wave per full triplet ------------
__global__ __launch_bounds__(256)
void triplet_full_kernel(const float* __restrict__ batch,
                         const int*   __restrict__ trip,
                         float*       __restrict__ partials, int T)
{
    const int lane = threadIdx.x & 63;
    const int wib  = threadIdx.x >> 6;
    const int wave_id = blockIdx.x * 4 + wib;
    const int n_waves = gridDim.x * 4;

    float acc = 0.0f;
    for (int t = wave_id; t < T; t += n_waves) {
        const int ia  = trip[3 * t + 0];
        const int ip  = trip[3 * t + 1];
        const int in_ = trip[3 * t + 2];
        const float4* A  = (const float4*)(batch + (size_t)ia * D);
        const float4* P  = (const float4*)(batch + (size_t)ip * D);
        const float4* Nv = (const float4*)(batch + (size_t)in_ * D);
        float dap = 0.0f, dan = 0.0f;
        #pragma unroll
        for (int c = 0; c < 4; ++c) {
            const int idx = lane + c * 64;
            float4 av = A[idx], pv = P[idx], nv = Nv[idx];
            float d;
            d = av.x - pv.x; dap += d * d;
            d = av.y - pv.y; dap += d * d;
            d = av.z - pv.z; dap += d * d;
            d = av.w - pv.w; dap += d * d;
            d = av.x - nv.x; dan += d * d;
            d = av.y - nv.y; dan += d * d;
            d = av.z - nv.z; dan += d * d;
            d = av.w - nv.w; dan += d * d;
        }
        float diff = dap - dan;
        #pragma unroll
        for (int off = 32; off > 0; off >>= 1) diff += __shfl_xor(diff, off, 64);
        const float loss = diff + MARGIN;
        acc += loss > 0.0f ? loss : 0.0f;
    }
    __shared__ float s[4];
    if (lane == 0) s[wib] = acc;
    __syncthreads();
    if (threadIdx.x == 0) partials[blockIdx.x] = (s[0] + s[1]) + (s[2] + s[3]);
}

extern "C" void kernel_launch(void* const* d_in, const int* in_sizes, int n_in,
                              void* d_out, int out_size, void* d_ws, size_t ws_size,
                              hipStream_t stream)
{
    const float* batch = (const float*)d_in[0];
    const int*   trip  = (const int*)d_in[1];
    float* out = (float*)d_out;
    const int T = in_sizes[1] / 3;

    const size_t need = ((size_t)NCHUNK * T + 256) * sizeof(float);
    if (ws_size >= need) {
        float* chunk_part = (float*)d_ws;            // [NCHUNK][T]
        float* part2      = chunk_part + (size_t)NCHUNK * T;  // [256]
        triplet_chunk_kernel<<<2048, 256, 0, stream>>>(batch, trip, chunk_part, T);
        chunk_reduce_kernel<<<256, 256, 0, stream>>>(chunk_part, part2, T);
        final_mean_kernel<<<1, 256, 0, stream>>>(part2, 256, out, 1.0f / (float)T);
    } else {
        // Workspace too small for chunk partials: single-pass fallback.
        float* partials = (float*)d_ws;
        triplet_full_kernel<<<2048, 256, 0, stream>>>(batch, trip, partials, T);
        final_mean_kernel<<<1, 256, 0, stream>>>(partials, 2048, out, 1.0f / (float)T);
    }
}

// Round 3
// 47.578 us; speedup vs baseline: 2.8736x; 1.1598x over previous
//
#include <hip/hip_runtime.h>

// Triplet margin loss: mean(relu(|a-p|^2 - |a-n|^2 + MARGIN)).
// batch: (N=4096, D=1024) fp32 (16 MB); triplets: (T=100000, 3) int32.
//
// R2 finding: XCD-pinned D-chunking made the gather L2-resident (FETCH
// 455 MB -> 13 MB), now L2-BW bound at ~21 TB/s moving 1.2 GB.
// R3 change: convert batch to bf16 once (8 MB), halving gather traffic to
// 0.6 GB; each XCD slice shrinks to 1 MB. 16-lane group reads one uint4
// (8 bf16) per row per triplet; unpack via shl/and; fp32 accumulate.

constexpr float MARGIN = 0.2f;
constexpr int D = 1024;
constexpr int NCHUNK = 8;            // = number of XCDs
constexpr int CHUNK = D / NCHUNK;    // 128 elements; 256 B in bf16

// ---------------- Phase 0: fp32 -> bf16 conversion (RNE) ----------------
__global__ __launch_bounds__(256)
void convert_bf16_kernel(const float* __restrict__ in,
                         ushort* __restrict__ out, int n4)
{
    const float4* in4 = (const float4*)in;
    ushort4* out4 = (ushort4*)out;
    int i = blockIdx.x * 256 + threadIdx.x;
    const int stride = gridDim.x * 256;
    for (; i < n4; i += stride) {
        float4 v = in4[i];
        ushort4 o;
        // round-to-nearest-even bf16
        uint u;
        u = __float_as_uint(v.x); o.x = (ushort)((u + 0x7fffu + ((u >> 16) & 1u)) >> 16);
        u = __float_as_uint(v.y); o.y = (ushort)((u + 0x7fffu + ((u >> 16) & 1u)) >> 16);
        u = __float_as_uint(v.z); o.z = (ushort)((u + 0x7fffu + ((u >> 16) & 1u)) >> 16);
        u = __float_as_uint(v.w); o.w = (ushort)((u + 0x7fffu + ((u >> 16) & 1u)) >> 16);
        out4[i] = o;
    }
}

// ---------------- Phase 1: per-(triplet, chunk) partial diffs ----------------
// 16 lanes per triplet-chunk; each lane reads one uint4 (8 bf16) per row.
__global__ __launch_bounds__(256)
void triplet_chunk_bf16_kernel(const ushort* __restrict__ batch16,
                               const int*   __restrict__ trip,
                               float*       __restrict__ chunk_part, // [NCHUNK][T]
                               int T)
{
    const int c     = blockIdx.x & (NCHUNK - 1);  // chunk == XCD (round-robin)
    const int bslot = blockIdx.x >> 3;
    const int nslot = gridDim.x >> 3;
    const int lane  = threadIdx.x & 63;
    const int wib   = threadIdx.x >> 6;
    const int g     = lane >> 4;                  // triplet subgroup (0..3)
    const int s     = lane & 15;                  // sublane within group

    // this lane's 16 B window within its chunk of any row
    const ushort* base = batch16 + c * CHUNK + s * 8;
    const int stride = nslot * 16;

    for (int t = bslot * 16 + wib * 4 + g; t < T; t += stride) {
        const int ia  = trip[3 * t + 0];
        const int ip  = trip[3 * t + 1];
        const int in_ = trip[3 * t + 2];

        const uint4 av = *(const uint4*)(base + (size_t)ia * D);
        const uint4 pv = *(const uint4*)(base + (size_t)ip * D);
        const uint4 nv = *(const uint4*)(base + (size_t)in_ * D);

        float dap = 0.0f, dan = 0.0f;
        #define ACC_PAIR(au, pu, nu)                                        \
        {                                                                    \
            const float al = __uint_as_float((au) << 16);                    \
            const float ah = __uint_as_float((au) & 0xffff0000u);            \
            const float pl = __uint_as_float((pu) << 16);                    \
            const float ph = __uint_as_float((pu) & 0xffff0000u);            \
            const float nl = __uint_as_float((nu) << 16);                    \
            const float nh = __uint_as_float((nu) & 0xffff0000u);            \
            float d;                                                         \
            d = al - pl; dap = fmaf(d, d, dap);                              \
            d = ah - ph; dap = fmaf(d, d, dap);                              \
            d = al - nl; dan = fmaf(d, d, dan);                              \
            d = ah - nh; dan = fmaf(d, d, dan);                              \
        }
        ACC_PAIR(av.x, pv.x, nv.x)
        ACC_PAIR(av.y, pv.y, nv.y)
        ACC_PAIR(av.z, pv.z, nv.z)
        ACC_PAIR(av.w, pv.w, nv.w)
        #undef ACC_PAIR

        // Reduce within the 16-lane group (xor offsets < 16 stay in-group).
        float diff = dap - dan;
        diff += __shfl_xor(diff, 1, 64);
        diff += __shfl_xor(diff, 2, 64);
        diff += __shfl_xor(diff, 4, 64);
        diff += __shfl_xor(diff, 8, 64);

        if (s == 0) chunk_part[(size_t)c * T + t] = diff;
    }
}

// ------------- Phase 2: sum chunks, margin+relu, per-block partial -----------
__global__ __launch_bounds__(256)
void chunk_reduce_kernel(const float* __restrict__ chunk_part,
                         float*       __restrict__ part2, int T)
{
    float acc = 0.0f;
    for (int t = blockIdx.x * 256 + threadIdx.x; t < T; t += gridDim.x * 256) {
        float sum = MARGIN;
        #pragma unroll
        for (int c = 0; c < NCHUNK; ++c) sum += chunk_part[(size_t)c * T + t];
        acc += sum > 0.0f ? sum : 0.0f;
    }
    __shared__ float s[256];
    s[threadIdx.x] = acc;
    __syncthreads();
    #pragma unroll
    for (int st = 128; st > 0; st >>= 1) {
        if (threadIdx.x < st) s[threadIdx.x] += s[threadIdx.x + st];
        __syncthreads();
    }
    if (threadIdx.x == 0) part2[blockIdx.x] = s[0];
}

// ---------------- Phase 3: final scalar ----------------
__global__ __launch_bounds__(256)
void final_mean_kernel(const float* __restrict__ part2, int n,
                       float* __restrict__ out, float invT)
{
    __shared__ float s[256];
    float acc = 0.0f;
    for (int i = threadIdx.x; i < n; i += 256) acc += part2[i];
    s[threadIdx.x] = acc;
    __syncthreads();
    #pragma unroll
    for (int st = 128; st > 0; st >>= 1) {
        if (threadIdx.x < st) s[threadIdx.x] += s[threadIdx.x + st];
        __syncthreads();
    }
    if (threadIdx.x == 0) out[0] = s[0] * invT;
}

// -------- Fallback phase 1 (R2, fp32): 16-lane group per triplet-chunk ------
__global__ __launch_bounds__(256)
void triplet_chunk_f32_kernel(const float* __restrict__ batch,
                              const int*   __restrict__ trip,
                              float*       __restrict__ chunk_part, int T)
{
    const int c     = blockIdx.x & (NCHUNK - 1);
    const int bslot = blockIdx.x >> 3;
    const int nslot = gridDim.x >> 3;
    const int lane  = threadIdx.x & 63;
    const int wib   = threadIdx.x >> 6;
    const int g     = lane >> 4;
    const int s     = lane & 15;

    const float* base = batch + c * CHUNK;
    const int stride = nslot * 16;

    for (int t = bslot * 16 + wib * 4 + g; t < T; t += stride) {
        const int ia  = trip[3 * t + 0];
        const int ip  = trip[3 * t + 1];
        const int in_ = trip[3 * t + 2];
        const float4* A  = (const float4*)(base + (size_t)ia * D);
        const float4* P  = (const float4*)(base + (size_t)ip * D);
        const float4* Nv = (const float4*)(base + (size_t)in_ * D);
        float dap = 0.0f, dan = 0.0f;
        #pragma unroll
        for (int k = 0; k < 2; ++k) {
            const int idx = s + k * 16;
            float4 av = A[idx], pv = P[idx], nv = Nv[idx];
            float d;
            d = av.x - pv.x; dap += d * d;
            d = av.y - pv.y; dap += d * d;
            d = av.z - pv.z; dap += d * d;
            d = av.w - pv.w; dap += d * d;
            d = av.x - nv.x; dan += d * d;
            d = av.y - nv.y; dan += d * d;
            d = av.z - nv.z; dan += d * d;
            d = av.w - nv.w; dan += d * d;
        }
        float diff = dap - dan;
        diff += __shfl_xor(diff, 1, 64);
        diff += __shfl_xor(diff, 2, 64);
        diff += __shfl_xor(diff, 4, 64);
        diff += __shfl_xor(diff, 8, 64);
        if (s == 0) chunk_part[(size_t)c * T + t] = diff;
    }
}

extern "C" void kernel_launch(void* const* d_in, const int* in_sizes, int n_in,
                              void* d_out, int out_size, void* d_ws, size_t ws_size,
                              hipStream_t stream)
{
    const float* batch = (const float*)d_in[0];
    const int*   trip  = (const int*)d_in[1];
    float* out = (float*)d_out;
    const int T  = in_sizes[1] / 3;
    const int ND = in_sizes[0];          // N*D

    const size_t bf16_bytes  = ((size_t)ND * 2 + 255) & ~(size_t)255;
    const size_t part_bytes  = (size_t)NCHUNK * T * sizeof(float);
    const size_t need_bf16   = bf16_bytes + part_bytes + 256 * sizeof(float);
    const size_t need_f32    = part_bytes + 256 * sizeof(float);

    if (ws_size >= need_bf16) {
        ushort* batch16   = (ushort*)d_ws;
        float* chunk_part = (float*)((char*)d_ws + bf16_bytes);
        float* part2      = chunk_part + (size_t)NCHUNK * T;
        convert_bf16_kernel<<<2048, 256, 0, stream>>>(batch, batch16, ND / 4);
        triplet_chunk_bf16_kernel<<<2048, 256, 0, stream>>>(batch16, trip, chunk_part, T);
        chunk_reduce_kernel<<<256, 256, 0, stream>>>(chunk_part, part2, T);
        final_mean_kernel<<<1, 256, 0, stream>>>(part2, 256, out, 1.0f / (float)T);
    } else if (ws_size >= need_f32) {
        float* chunk_part = (float*)d_ws;
        float* part2      = chunk_part + (size_t)NCHUNK * T;
        triplet_chunk_f32_kernel<<<2048, 256, 0, stream>>>(batch, trip, chunk_part, T);
        chunk_reduce_kernel<<<256, 256, 0, stream>>>(chunk_part, part2, T);
        final_mean_kernel<<<1, 256, 0, stream>>>(part2, 256, out, 1.0f / (float)T);
    }
}

// Round 4
// 36.529 us; speedup vs baseline: 3.7427x; 1.3025x over previous
//
#include <hip/hip_runtime.h>

// Triplet margin loss: mean(relu(|a-p|^2 - |a-n|^2 + MARGIN)).
// batch: (N=4096, D=1024) fp32 (16 MB); triplets: (T=100000, 3) int32.
//
// Ladder: R1 naive gather 137us (L3-thrash, 455MB refetch) -> R2 XCD-pinned
// D-chunks 55us (L2-resident, ~21 TB/s) -> R3 bf16 47.6us (0.6 GB gathers).
// R4: fp8 e4m3 via HW converters; gather traffic 0.3 GB; NCHUNK=4 so each
// 16-lane group still reads one uint4 (16 fp8) per row; per-XCD slice 1 MB.

constexpr float MARGIN = 0.2f;
constexpr int D = 1024;

typedef float f32x2 __attribute__((ext_vector_type(2)));

// ---------------- Phase 0: fp32 -> fp8 e4m3 (HW RNE converter) ----------------
__global__ __launch_bounds__(256)
void convert_fp8_kernel(const float* __restrict__ in,
                        uint* __restrict__ out, int n4)
{
    const float4* in4 = (const float4*)in;
    int i = blockIdx.x * 256 + threadIdx.x;
    const int stride = gridDim.x * 256;
    for (; i < n4; i += stride) {
        float4 v = in4[i];
        uint u = 0;
        u = (uint)__builtin_amdgcn_cvt_pk_fp8_f32(v.x, v.y, (int)u, false);
        u = (uint)__builtin_amdgcn_cvt_pk_fp8_f32(v.z, v.w, (int)u, true);
        out[i] = u;
    }
}

// ---------------- Phase 1: per-(triplet, chunk) partial diffs ----------------
// NCHUNK=4 chunks of 256 fp8 (256 B); chunk = blockIdx & 3 -> XCD k&3 owns
// chunk k&3 (1 MB slice, L2-resident). 16 lanes per triplet-chunk; each lane
// loads one uint4 (16 fp8) per row.
__device__ __forceinline__ void acc_u(uint ua, uint up, uint un,
                                      float& dap, float& dan)
{
    f32x2 a0 = __builtin_amdgcn_cvt_pk_f32_fp8((int)ua, false);
    f32x2 a1 = __builtin_amdgcn_cvt_pk_f32_fp8((int)ua, true);
    f32x2 p0 = __builtin_amdgcn_cvt_pk_f32_fp8((int)up, false);
    f32x2 p1 = __builtin_amdgcn_cvt_pk_f32_fp8((int)up, true);
    f32x2 n0 = __builtin_amdgcn_cvt_pk_f32_fp8((int)un, false);
    f32x2 n1 = __builtin_amdgcn_cvt_pk_f32_fp8((int)un, true);
    float d;
    d = a0.x - p0.x; dap = fmaf(d, d, dap);
    d = a0.y - p0.y; dap = fmaf(d, d, dap);
    d = a1.x - p1.x; dap = fmaf(d, d, dap);
    d = a1.y - p1.y; dap = fmaf(d, d, dap);
    d = a0.x - n0.x; dan = fmaf(d, d, dan);
    d = a0.y - n0.y; dan = fmaf(d, d, dan);
    d = a1.x - n1.x; dan = fmaf(d, d, dan);
    d = a1.y - n1.y; dan = fmaf(d, d, dan);
}

__global__ __launch_bounds__(256)
void triplet_chunk_fp8_kernel(const unsigned char* __restrict__ batch8,
                              const int*   __restrict__ trip,
                              float*       __restrict__ chunk_part, // [4][T]
                              int T)
{
    const int c     = blockIdx.x & 3;             // chunk; XCD k -> chunk k&3
    const int bslot = blockIdx.x >> 2;
    const int nslot = gridDim.x >> 2;
    const int lane  = threadIdx.x & 63;
    const int wib   = threadIdx.x >> 6;
    const int g     = lane >> 4;                  // triplet subgroup (0..3)
    const int s     = lane & 15;                  // sublane within group

    // this lane's 16 B window (16 fp8) within chunk c of any row
    const unsigned char* base = batch8 + c * (D / 4) + s * 16;
    const int stride = nslot * 16;

    for (int t = bslot * 16 + wib * 4 + g; t < T; t += stride) {
        const int ia  = trip[3 * t + 0];
        const int ip  = trip[3 * t + 1];
        const int in_ = trip[3 * t + 2];

        const uint4 av = *(const uint4*)(base + (size_t)ia * D);
        const uint4 pv = *(const uint4*)(base + (size_t)ip * D);
        const uint4 nv = *(const uint4*)(base + (size_t)in_ * D);

        float dap = 0.0f, dan = 0.0f;
        acc_u(av.x, pv.x, nv.x, dap, dan);
        acc_u(av.y, pv.y, nv.y, dap, dan);
        acc_u(av.z, pv.z, nv.z, dap, dan);
        acc_u(av.w, pv.w, nv.w, dap, dan);

        // Reduce within the 16-lane group.
        float diff = dap - dan;
        diff += __shfl_xor(diff, 1, 64);
        diff += __shfl_xor(diff, 2, 64);
        diff += __shfl_xor(diff, 4, 64);
        diff += __shfl_xor(diff, 8, 64);

        if (s == 0) chunk_part[(size_t)c * T + t] = diff;
    }
}

// ------------- Phase 2: sum chunks, margin+relu, per-block partial -----------
template<int NC>
__global__ __launch_bounds__(256)
void chunk_reduce_kernel(const float* __restrict__ chunk_part,
                         float*       __restrict__ part2, int T)
{
    float acc = 0.0f;
    for (int t = blockIdx.x * 256 + threadIdx.x; t < T; t += gridDim.x * 256) {
        float sum = MARGIN;
        #pragma unroll
        for (int c = 0; c < NC; ++c) sum += chunk_part[(size_t)c * T + t];
        acc += sum > 0.0f ? sum : 0.0f;
    }
    __shared__ float s[256];
    s[threadIdx.x] = acc;
    __syncthreads();
    #pragma unroll
    for (int st = 128; st > 0; st >>= 1) {
        if (threadIdx.x < st) s[threadIdx.x] += s[threadIdx.x + st];
        __syncthreads();
    }
    if (threadIdx.x == 0) part2[blockIdx.x] = s[0];
}

// ---------------- Phase 3: final scalar ----------------
__global__ __launch_bounds__(256)
void final_mean_kernel(const float* __restrict__ part2, int n,
                       float* __restrict__ out, float invT)
{
    __shared__ float s[256];
    float acc = 0.0f;
    for (int i = threadIdx.x; i < n; i += 256) acc += part2[i];
    s[threadIdx.x] = acc;
    __syncthreads();
    #pragma unroll
    for (int st = 128; st > 0; st >>= 1) {
        if (threadIdx.x < st) s[threadIdx.x] += s[threadIdx.x + st];
        __syncthreads();
    }
    if (threadIdx.x == 0) out[0] = s[0] * invT;
}

// -------- Fallback phase 1 (fp32, NCHUNK=8): in case ws is too small --------
__global__ __launch_bounds__(256)
void triplet_chunk_f32_kernel(const float* __restrict__ batch,
                              const int*   __restrict__ trip,
                              float*       __restrict__ chunk_part, int T)
{
    const int c     = blockIdx.x & 7;
    const int bslot = blockIdx.x >> 3;
    const int nslot = gridDim.x >> 3;
    const int lane  = threadIdx.x & 63;
    const int wib   = threadIdx.x >> 6;
    const int g     = lane >> 4;
    const int s     = lane & 15;

    const float* base = batch + c * (D / 8);
    const int stride = nslot * 16;

    for (int t = bslot * 16 + wib * 4 + g; t < T; t += stride) {
        const int ia  = trip[3 * t + 0];
        const int ip  = trip[3 * t + 1];
        const int in_ = trip[3 * t + 2];
        const float4* A  = (const float4*)(base + (size_t)ia * D);
        const float4* P  = (const float4*)(base + (size_t)ip * D);
        const float4* Nv = (const float4*)(base + (size_t)in_ * D);
        float dap = 0.0f, dan = 0.0f;
        #pragma unroll
        for (int k = 0; k < 2; ++k) {
            const int idx = s + k * 16;
            float4 av = A[idx], pv = P[idx], nv = Nv[idx];
            float d;
            d = av.x - pv.x; dap += d * d;
            d = av.y - pv.y; dap += d * d;
            d = av.z - pv.z; dap += d * d;
            d = av.w - pv.w; dap += d * d;
            d = av.x - nv.x; dan += d * d;
            d = av.y - nv.y; dan += d * d;
            d = av.z - nv.z; dan += d * d;
            d = av.w - nv.w; dan += d * d;
        }
        float diff = dap - dan;
        diff += __shfl_xor(diff, 1, 64);
        diff += __shfl_xor(diff, 2, 64);
        diff += __shfl_xor(diff, 4, 64);
        diff += __shfl_xor(diff, 8, 64);
        if (s == 0) chunk_part[(size_t)c * T + t] = diff;
    }
}

extern "C" void kernel_launch(void* const* d_in, const int* in_sizes, int n_in,
                              void* d_out, int out_size, void* d_ws, size_t ws_size,
                              hipStream_t stream)
{
    const float* batch = (const float*)d_in[0];
    const int*   trip  = (const int*)d_in[1];
    float* out = (float*)d_out;
    const int T  = in_sizes[1] / 3;
    const int ND = in_sizes[0];          // N*D

    const size_t fp8_bytes  = ((size_t)ND + 255) & ~(size_t)255;
    const size_t need_fp8   = fp8_bytes + (size_t)4 * T * sizeof(float) + 256 * sizeof(float);
    const size_t need_f32   = (size_t)8 * T * sizeof(float) + 256 * sizeof(float);

    if (ws_size >= need_fp8) {
        unsigned char* batch8 = (unsigned char*)d_ws;
        float* chunk_part = (float*)((char*)d_ws + fp8_bytes);   // [4][T]
        float* part2      = chunk_part + (size_t)4 * T;
        convert_fp8_kernel<<<2048, 256, 0, stream>>>(batch, (uint*)batch8, ND / 4);
        triplet_chunk_fp8_kernel<<<2048, 256, 0, stream>>>(batch8, trip, chunk_part, T);
        chunk_reduce_kernel<4><<<256, 256, 0, stream>>>(chunk_part, part2, T);
        final_mean_kernel<<<1, 256, 0, stream>>>(part2, 256, out, 1.0f / (float)T);
    } else if (ws_size >= need_f32) {
        float* chunk_part = (float*)d_ws;                         // [8][T]
        float* part2      = chunk_part + (size_t)8 * T;
        triplet_chunk_f32_kernel<<<2048, 256, 0, stream>>>(batch, trip, chunk_part, T);
        chunk_reduce_kernel<8><<<256, 256, 0, stream>>>(chunk_part, part2, T);
        final_mean_kernel<<<1, 256, 0, stream>>>(part2, 256, out, 1.0f / (float)T);
    }
}

// Round 5
// 34.904 us; speedup vs baseline: 3.9170x; 1.0466x over previous
//
#include <hip/hip_runtime.h>

// Triplet margin loss: mean(relu(|a-p|^2 - |a-n|^2 + MARGIN)).
// batch: (N=4096, D=1024) fp32 (16 MB); triplets: (T=100000, 3) int32.
//
// Ladder: R1 naive 137us (L3 thrash) -> R2 XCD D-chunks 55us (L2-resident)
// -> R3 bf16 47.6us -> R4 fp8 chunked 36.5us (VALU/L2 mixed).
// R5: (a) identity d_ap-d_an = |p|^2-|n|^2 + 2a.(n-p): one accumulator,
//     14 VALU per 4 elems instead of 22; exact fp32 norms folded into the
//     convert pass (free - it already reads all 16 MB).
// (b) fp8 batch is 4 MB -> fits EVERY XCD's private L2: no chunking, no
//     phase-2 kernel. One wave per triplet; 64 lanes x 16B = one full row.

constexpr float MARGIN = 0.2f;
constexpr int D = 1024;

typedef float f32x2 __attribute__((ext_vector_type(2)));

// ---- Phase 0: one wave per row: fp32 -> fp8 e4m3 (HW RNE) + fp32 row norm ---
__global__ __launch_bounds__(256)
void convert_norm_kernel(const float* __restrict__ in,
                         uint* __restrict__ out8,
                         float* __restrict__ norms, int nrows)
{
    const int lane = threadIdx.x & 63;
    const int wib  = threadIdx.x >> 6;
    const int nw   = gridDim.x * 4;
    for (int row = blockIdx.x * 4 + wib; row < nrows; row += nw) {
        const float4* r4 = (const float4*)(in + (size_t)row * D);
        uint* o = out8 + (size_t)row * (D / 4);
        float nrm = 0.0f;
        #pragma unroll
        for (int k = 0; k < 4; ++k) {
            const float4 v = r4[lane + 64 * k];     // contiguous per instr
            uint u = 0;
            u = (uint)__builtin_amdgcn_cvt_pk_fp8_f32(v.x, v.y, (int)u, false);
            u = (uint)__builtin_amdgcn_cvt_pk_fp8_f32(v.z, v.w, (int)u, true);
            o[lane + 64 * k] = u;
            nrm = fmaf(v.x, v.x, fmaf(v.y, v.y, fmaf(v.z, v.z, fmaf(v.w, v.w, nrm))));
        }
        #pragma unroll
        for (int off = 32; off > 0; off >>= 1) nrm += __shfl_xor(nrm, off, 64);
        if (lane == 0) norms[row] = nrm;
    }
}

// ---- Phase 1: one wave per triplet; dot = a.(n-p) over the full row --------
__device__ __forceinline__ void dot_u(uint ua, uint up, uint un, float& dot)
{
    const f32x2 a0 = __builtin_amdgcn_cvt_pk_f32_fp8((int)ua, false);
    const f32x2 a1 = __builtin_amdgcn_cvt_pk_f32_fp8((int)ua, true);
    const f32x2 p0 = __builtin_amdgcn_cvt_pk_f32_fp8((int)up, false);
    const f32x2 p1 = __builtin_amdgcn_cvt_pk_f32_fp8((int)up, true);
    const f32x2 n0 = __builtin_amdgcn_cvt_pk_f32_fp8((int)un, false);
    const f32x2 n1 = __builtin_amdgcn_cvt_pk_f32_fp8((int)un, true);
    dot = fmaf(a0.x, n0.x - p0.x, dot);
    dot = fmaf(a0.y, n0.y - p0.y, dot);
    dot = fmaf(a1.x, n1.x - p1.x, dot);
    dot = fmaf(a1.y, n1.y - p1.y, dot);
}

__global__ __launch_bounds__(256)
void triplet_dot_kernel(const unsigned char* __restrict__ batch8,
                        const int*   __restrict__ trip,
                        const float* __restrict__ norms,
                        float*       __restrict__ partials, int T)
{
    const int lane = threadIdx.x & 63;
    const int wib  = threadIdx.x >> 6;
    const int wave_id = blockIdx.x * 4 + wib;
    const int n_waves = gridDim.x * 4;

    const unsigned char* base = batch8 + lane * 16;  // lane's 16B of any row

    float acc = 0.0f;
    for (int t = wave_id; t < T; t += n_waves) {
        const int ia  = trip[3 * t + 0];
        const int ip  = trip[3 * t + 1];
        const int in_ = trip[3 * t + 2];

        const uint4 av = *(const uint4*)(base + (size_t)ia * D);
        const uint4 pv = *(const uint4*)(base + (size_t)ip * D);
        const uint4 nv = *(const uint4*)(base + (size_t)in_ * D);

        float dot = 0.0f;
        dot_u(av.x, pv.x, nv.x, dot);
        dot_u(av.y, pv.y, nv.y, dot);
        dot_u(av.z, pv.z, nv.z, dot);
        dot_u(av.w, pv.w, nv.w, dot);

        #pragma unroll
        for (int off = 32; off > 0; off >>= 1) dot += __shfl_xor(dot, off, 64);

        const float loss = norms[ip] - norms[in_] + 2.0f * dot + MARGIN;
        acc += loss > 0.0f ? loss : 0.0f;
    }

    __shared__ float s[4];
    if (lane == 0) s[wib] = acc;
    __syncthreads();
    if (threadIdx.x == 0)
        partials[blockIdx.x] = (s[0] + s[1]) + (s[2] + s[3]);
}

// ---- Phase 2: final scalar ----
__global__ __launch_bounds__(256)
void final_mean_kernel(const float* __restrict__ part, int n,
                       float* __restrict__ out, float invT)
{
    __shared__ float s[256];
    float acc = 0.0f;
    for (int i = threadIdx.x; i < n; i += 256) acc += part[i];
    s[threadIdx.x] = acc;
    __syncthreads();
    #pragma unroll
    for (int st = 128; st > 0; st >>= 1) {
        if (threadIdx.x < st) s[threadIdx.x] += s[threadIdx.x + st];
        __syncthreads();
    }
    if (threadIdx.x == 0) out[0] = s[0] * invT;
}

// ---- Fallback (fp32, one wave per triplet, tiny ws): R1 kernel -------------
__global__ __launch_bounds__(256)
void triplet_full_kernel(const float* __restrict__ batch,
                         const int*   __restrict__ trip,
                         float*       __restrict__ partials, int T)
{
    const int lane = threadIdx.x & 63;
    const int wib  = threadIdx.x >> 6;
    const int wave_id = blockIdx.x * 4 + wib;
    const int n_waves = gridDim.x * 4;

    float acc = 0.0f;
    for (int t = wave_id; t < T; t += n_waves) {
        const int ia  = trip[3 * t + 0];
        const int ip  = trip[3 * t + 1];
        const int in_ = trip[3 * t + 2];
        const float4* A  = (const float4*)(batch + (size_t)ia * D);
        const float4* P  = (const float4*)(batch + (size_t)ip * D);
        const float4* Nv = (const float4*)(batch + (size_t)in_ * D);
        float dap = 0.0f, dan = 0.0f;
        #pragma unroll
        for (int c = 0; c < 4; ++c) {
            const int idx = lane + c * 64;
            float4 av = A[idx], pv = P[idx], nv = Nv[idx];
            float d;
            d = av.x - pv.x; dap += d * d;
            d = av.y - pv.y; dap += d * d;
            d = av.z - pv.z; dap += d * d;
            d = av.w - pv.w; dap += d * d;
            d = av.x - nv.x; dan += d * d;
            d = av.y - nv.y; dan += d * d;
            d = av.z - nv.z; dan += d * d;
            d = av.w - nv.w; dan += d * d;
        }
        float diff = dap - dan;
        #pragma unroll
        for (int off = 32; off > 0; off >>= 1) diff += __shfl_xor(diff, off, 64);
        const float loss = diff + MARGIN;
        acc += loss > 0.0f ? loss : 0.0f;
    }
    __shared__ float s[4];
    if (lane == 0) s[wib] = acc;
    __syncthreads();
    if (threadIdx.x == 0) partials[blockIdx.x] = (s[0] + s[1]) + (s[2] + s[3]);
}

extern "C" void kernel_launch(void* const* d_in, const int* in_sizes, int n_in,
                              void* d_out, int out_size, void* d_ws, size_t ws_size,
                              hipStream_t stream)
{
    const float* batch = (const float*)d_in[0];
    const int*   trip  = (const int*)d_in[1];
    float* out = (float*)d_out;
    const int T     = in_sizes[1] / 3;
    const int ND    = in_sizes[0];       // N*D
    const int nrows = ND / D;

    const int BLOCKS = 2048;
    const size_t fp8_bytes  = ((size_t)ND + 255) & ~(size_t)255;
    const size_t norm_bytes = ((size_t)nrows * sizeof(float) + 255) & ~(size_t)255;
    const size_t need = fp8_bytes + norm_bytes + (size_t)BLOCKS * sizeof(float);

    if (ws_size >= need) {
        unsigned char* batch8 = (unsigned char*)d_ws;
        float* norms    = (float*)((char*)d_ws + fp8_bytes);
        float* partials = (float*)((char*)d_ws + fp8_bytes + norm_bytes);
        convert_norm_kernel<<<1024, 256, 0, stream>>>(batch, (uint*)batch8, norms, nrows);
        triplet_dot_kernel<<<BLOCKS, 256, 0, stream>>>(batch8, trip, norms, partials, T);
        final_mean_kernel<<<1, 256, 0, stream>>>(partials, BLOCKS, out, 1.0f / (float)T);
    } else {
        float* partials = (float*)d_ws;  // 8 KB
        triplet_full_kernel<<<BLOCKS, 256, 0, stream>>>(batch, trip, partials, T);
        final_mean_kernel<<<1, 256, 0, stream>>>(partials, BLOCKS, out, 1.0f / (float)T);
    }
}